// Round 1
// baseline (24143.977 us; speedup 1.0000x reference)
//
#include <hip/hip_runtime.h>

typedef unsigned short u16;
typedef __attribute__((ext_vector_type(8))) __bf16 bf16x8;
typedef __attribute__((ext_vector_type(4))) float f32x4;

// Problem constants
#define NWG 256
#define CHUNK 64          // timesteps per chunk (Xp chunk = 32 MiB bf16)
#define NCHUNK 16

__device__ __forceinline__ u16 f2b(float f) {
  union { float f; unsigned u; } v; v.f = f;
  unsigned r = (v.u + 0x7fffu + ((v.u >> 16) & 1u)) >> 16;
  return (u16)r;
}
__device__ __forceinline__ float b2f(u16 u) {
  union { unsigned u; float f; } v; v.u = ((unsigned)u) << 16;
  return v.f;
}
__device__ __forceinline__ float sig(float x) { return 1.0f / (1.0f + __expf(-x)); }
__device__ __forceinline__ float tanh_(float x) { return 2.0f / (1.0f + __expf(-2.0f * x)) - 1.0f; }

// ---------------------------------------------------------------------------
// prep: Wc[4096][2048] bf16 = [W_ih | W_hh]; bias = b_ih + b_hh (fp32);
//       hbuf parity-0 = bf16(h0); cst = c0 (fp32)
// ---------------------------------------------------------------------------
__global__ __launch_bounds__(256) void prep_kernel(
    const float* __restrict__ W_ih, const float* __restrict__ W_hh,
    const float* __restrict__ b_ih, const float* __restrict__ b_hh,
    const float* __restrict__ h0, const float* __restrict__ c0,
    u16* __restrict__ Wc, float* __restrict__ bias,
    u16* __restrict__ hbuf, float* __restrict__ cst)
{
  const int tid = threadIdx.x;
  const int blk = blockIdx.x;
  // weight row blk
  {
    const float4 a = *reinterpret_cast<const float4*>(W_ih + (size_t)blk * 1024 + tid * 4);
    const float4 b = *reinterpret_cast<const float4*>(W_hh + (size_t)blk * 1024 + tid * 4);
    u16* dst = Wc + (size_t)blk * 2048;
    *reinterpret_cast<ushort4*>(dst + tid * 4) =
        make_ushort4(f2b(a.x), f2b(a.y), f2b(a.z), f2b(a.w));
    *reinterpret_cast<ushort4*>(dst + 1024 + tid * 4) =
        make_ushort4(f2b(b.x), f2b(b.y), f2b(b.z), f2b(b.w));
  }
  if (blk < 16) {
    int i = blk * 256 + tid;
    bias[i] = b_ih[i] + b_hh[i];
  } else if (blk < 80) {
    int row = blk - 16, k = tid * 4;
    float4 v = *reinterpret_cast<const float4*>(h0 + (size_t)row * 1024 + k);
    *reinterpret_cast<ushort4*>(hbuf + (size_t)row * 1024 + k) =
        make_ushort4(f2b(v.x), f2b(v.y), f2b(v.z), f2b(v.w));
  } else if (blk < 144) {
    int row = blk - 80, k = tid * 4;
    *reinterpret_cast<float4*>(cst + (size_t)row * 1024 + k) =
        *reinterpret_cast<const float4*>(c0 + (size_t)row * 1024 + k);
  }
}

// ---------------------------------------------------------------------------
// xproj: Xp[m][n] = sum_k x_chunk[m][k] * Wc[n][k]   (m = (t-t0)*64+b, chunk M=4096)
// 128x128 tile, 4 waves 2x2, K staged in 64-chunks, bf16 MFMA 16x16x32.
// ---------------------------------------------------------------------------
__global__ __launch_bounds__(256) void xproj_kernel(
    const float* __restrict__ xc, const u16* __restrict__ Wc, u16* __restrict__ Xp)
{
  __shared__ __align__(16) u16 As[128][72];   // pitch 72 -> 2-way (free) bank aliasing
  __shared__ __align__(16) u16 Bs[128][72];
  const int tid = threadIdx.x;
  const int w = tid >> 6, l = tid & 63;
  const int bm = blockIdx.x & 31;        // 32 m-tiles (M=4096)
  const int bn = blockIdx.x >> 5;        // 32 n-tiles (N=4096)
  const int m0 = bm << 7, n0 = bn << 7;
  const int wm = w & 1, wn = w >> 1;
  const int lr = l & 15, lq = l >> 4;

  f32x4 acc[4][4];
  for (int i = 0; i < 4; ++i)
    for (int j = 0; j < 4; ++j) acc[i][j] = (f32x4){0.f, 0.f, 0.f, 0.f};

  for (int kc = 0; kc < 1024; kc += 64) {
    {  // stage A (fp32 -> bf16): 128 rows x 64 k
      const int k4 = (tid & 15) << 2;
      const int rb = tid >> 4;
      for (int rp = 0; rp < 128; rp += 16) {
        int row = rp + rb;
        float4 v = *reinterpret_cast<const float4*>(xc + (size_t)(m0 + row) * 1024 + kc + k4);
        unsigned lo = (unsigned)f2b(v.x) | ((unsigned)f2b(v.y) << 16);
        unsigned hi = (unsigned)f2b(v.z) | ((unsigned)f2b(v.w) << 16);
        *reinterpret_cast<uint2*>(&As[row][k4]) = make_uint2(lo, hi);
      }
    }
    {  // stage B (already bf16): 128 rows x 64 k
      const int kk = (tid & 7) << 3;
      const int rb = tid >> 3;
      for (int rp = 0; rp < 128; rp += 32) {
        int row = rp + rb;
        uint4 v = *reinterpret_cast<const uint4*>(Wc + (size_t)(n0 + row) * 2048 + kc + kk);
        *reinterpret_cast<uint4*>(&Bs[row][kk]) = v;
      }
    }
    __syncthreads();
    for (int kb = 0; kb < 2; ++kb) {
      const int ko = kb * 32 + lq * 8;
      bf16x8 af[4], bfr[4];
      for (int i = 0; i < 4; ++i)
        af[i] = *reinterpret_cast<const bf16x8*>(&As[(wm << 6) + (i << 4) + lr][ko]);
      for (int j = 0; j < 4; ++j)
        bfr[j] = *reinterpret_cast<const bf16x8*>(&Bs[(wn << 6) + (j << 4) + lr][ko]);
      for (int i = 0; i < 4; ++i)
        for (int j = 0; j < 4; ++j)
          acc[i][j] = __builtin_amdgcn_mfma_f32_16x16x32_bf16(af[i], bfr[j], acc[i][j], 0, 0, 0);
    }
    __syncthreads();
  }
  // epilogue: D row = (lane>>4)*4 + reg, col = lane&15  [guide-verified]
  for (int i = 0; i < 4; ++i)
    for (int j = 0; j < 4; ++j) {
      int row0 = m0 + (wm << 6) + (i << 4) + lq * 4;
      int coln = n0 + (wn << 6) + (j << 4) + lr;
      for (int r = 0; r < 4; ++r)
        Xp[(size_t)(row0 + r) * 4096 + coln] = f2b(acc[i][j][r]);
    }
}

// ---------------------------------------------------------------------------
// scan: persistent, 256 WGs. WG g owns h-cols [4g,4g+4) -> 16 gate cols.
// W_hh slice lives in LDS (fragment order). One grid barrier per step.
// ---------------------------------------------------------------------------
__global__ __launch_bounds__(256) void scan_kernel(
    const u16* __restrict__ Wc, const u16* __restrict__ Xp,
    u16* __restrict__ hbuf, float* __restrict__ cst, const float* __restrict__ bias,
    float* __restrict__ out, float* __restrict__ outT, float* __restrict__ cT,
    unsigned* __restrict__ bar, int t0, int C)
{
  __shared__ __align__(16) u16 Wlds[32 * 64 * 8];  // [kb][lane][8] fragment order, 32 KB
  const int tid = threadIdx.x;
  const int g = blockIdx.x;
  const int w = tid >> 6, l = tid & 63;
  const int n = l & 15, kq = l >> 4;
  const int jj = (g << 2) + (n & 3);              // h-column for this lane (if n<4: n&3==n)
  const int col = ((n >> 2) << 10) + jj;          // gate column: gate = n>>2 (i,f,g,o)

  // load W_hh slice into LDS in B-fragment order: B[k][n] = Wc[col(n)][1024+k]
  for (int i = tid; i < 2048; i += 256) {
    int kb = i >> 6, l2 = i & 63;
    int nn = l2 & 15, kq2 = l2 >> 4;
    int c2 = ((nn >> 2) << 10) + (g << 2) + (nn & 3);
    uint4 v = *reinterpret_cast<const uint4*>(Wc + (size_t)c2 * 2048 + 1024 + kb * 32 + kq2 * 8);
    *reinterpret_cast<uint4*>(&Wlds[i * 8]) = v;
  }
  const float biasv = bias[col];
  const int brow = (w << 4) + (kq << 2);          // batch row base for D regs
  float creg[4];
  if (n < 4)
    for (int r = 0; r < 4; ++r) creg[r] = cst[(size_t)(brow + r) * 1024 + jj];
  __syncthreads();

  for (int ts = 0; ts < C; ++ts) {
    const int t = t0 + ts;
    const u16* hs = hbuf + ((t & 1) ? 65536 : 0);
    u16* hd = hbuf + ((t & 1) ? 0 : 65536);
    // A-fragment directly from global h: A[m=lane&15][k=(lane>>4)*8+j]
    const u16* arow = hs + (size_t)((w << 4) + n) * 1024 + (kq << 3);
    f32x4 acc = {0.f, 0.f, 0.f, 0.f};
#pragma unroll 8
    for (int kb = 0; kb < 32; ++kb) {
      bf16x8 a = *reinterpret_cast<const bf16x8*>(arow + (kb << 5));
      bf16x8 wf = *reinterpret_cast<const bf16x8*>(&Wlds[((kb << 6) + l) << 3]);
      acc = __builtin_amdgcn_mfma_f32_16x16x32_bf16(a, wf, acc, 0, 0, 0);
    }
    // gate preacts for all lanes (lanes n>=4 are shuffle sources)
    float gv[4];
    const u16* xpr = Xp + ((size_t)(ts * 64 + brow) << 12) + col;
    for (int r = 0; r < 4; ++r) gv[r] = acc[r] + b2f(xpr[(size_t)r << 12]) + biasv;
    const int sb = (l & 48) | (n & 3);
    float fp[4], gp[4], op[4];
    for (int r = 0; r < 4; ++r) {
      fp[r] = __shfl(gv[r], sb + 4);
      gp[r] = __shfl(gv[r], sb + 8);
      op[r] = __shfl(gv[r], sb + 12);
    }
    if (n < 4) {
      for (int r = 0; r < 4; ++r) {
        float iv = sig(gv[r]);
        float fv = sig(fp[r]);
        float gg = tanh_(gp[r]);
        float ov = sig(op[r]);
        float cn = fv * creg[r] + iv * gg;
        float hv = ov * tanh_(cn);
        creg[r] = cn;
        int b = brow + r;
        hd[(size_t)b * 1024 + jj] = f2b(hv);
        out[((size_t)t * 64 + b) * 1024 + jj] = hv;
        if (t == 1023) outT[(size_t)b * 1024 + jj] = hv;
      }
    }
    // grid barrier (monotonic counter; target = 256 arrivals per global step)
    __syncthreads();
    if (tid == 0) {
      __threadfence();
      atomicAdd(bar, 1u);
      const unsigned target = (unsigned)(t + 1) * 256u;
      while (__hip_atomic_load(bar, __ATOMIC_ACQUIRE, __HIP_MEMORY_SCOPE_AGENT) < target)
        __builtin_amdgcn_s_sleep(1);
    }
    __syncthreads();
  }
  if (n < 4) {
    for (int r = 0; r < 4; ++r) cst[(size_t)(brow + r) * 1024 + jj] = creg[r];
    if (t0 + C == 1024)
      for (int r = 0; r < 4; ++r) cT[(size_t)(brow + r) * 1024 + jj] = creg[r];
  }
}

// ---------------------------------------------------------------------------
extern "C" void kernel_launch(void* const* d_in, const int* in_sizes, int n_in,
                              void* d_out, int out_size, void* d_ws, size_t ws_size,
                              hipStream_t stream)
{
  const float* x    = (const float*)d_in[0];
  const float* W_ih = (const float*)d_in[1];
  const float* W_hh = (const float*)d_in[2];
  const float* b_ih = (const float*)d_in[3];
  const float* b_hh = (const float*)d_in[4];
  const float* h0   = (const float*)d_in[5];
  const float* c0   = (const float*)d_in[6];
  float* out  = (float*)d_out;
  float* outT = out + (size_t)1024 * 64 * 1024;   // h_T
  float* cT   = outT + 64 * 1024;                 // c_T

  unsigned char* ws = (unsigned char*)d_ws;
  size_t off = 0;
  u16* Wc = (u16*)(ws + off);      off += (size_t)4096 * 2048 * 2;  // 16 MiB
  float* bias = (float*)(ws + off); off += 4096 * 4;
  u16* hbuf = (u16*)(ws + off);    off += (size_t)2 * 65536 * 2;    // ping-pong h (bf16)
  float* cst = (float*)(ws + off); off += (size_t)65536 * 4;        // c state
  unsigned* bar = (unsigned*)(ws + off); off += 256;
  u16* Xp = (u16*)(ws + off);      // 32 MiB chunk buffer; total ws need ~49 MiB

  hipMemsetAsync(bar, 0, 256, stream);
  hipLaunchKernelGGL(prep_kernel, dim3(4096), dim3(256), 0, stream,
                     W_ih, W_hh, b_ih, b_hh, h0, c0, Wc, bias, hbuf, cst);

  for (int c = 0; c < NCHUNK; ++c) {
    int t0 = c * CHUNK;
    hipLaunchKernelGGL(xproj_kernel, dim3(1024), dim3(256), 0, stream,
                       x + (size_t)t0 * 65536, Wc, Xp);
    int C = CHUNK;
    void* args[] = {&Wc, &Xp, &hbuf, &cst, &bias, &out, &outT, &cT, &bar, &t0, &C};
    if (hipLaunchCooperativeKernel(reinterpret_cast<void*>(scan_kernel),
                                   dim3(NWG), dim3(256), args, 0, stream) != hipSuccess) {
      (void)hipGetLastError();
      hipLaunchKernelGGL(scan_kernel, dim3(NWG), dim3(256), 0, stream,
                         Wc, Xp, hbuf, cst, bias, out, outT, cT, bar, t0, CHUNK);
    }
  }
}